// Round 3
// baseline (34.273 us; speedup 1.0000x reference)
//
#include <hip/hip_runtime.h>

// Problem constants (from reference):
//   B=8, V=6890, C=16, F=13776, FTOT=B*F=110208, H=W=512, K=1
//   npix = B*H*W*K = 2,097,152
// Output: int32 [B,H,W,K] = channel 0 of barycentric-interpolated
// per-vertex class features, truncated toward zero; 0 for background.

#define VC_C 16

// Native clang vector types — required for __builtin_nontemporal_*.
typedef int   vint4   __attribute__((ext_vector_type(4)));
typedef float vfloat4 __attribute__((ext_vector_type(4)));

// Kernel 1: pre-gather channel-0 vertex attribute for each face's 3 verts
// into a compact float4 table (L2-resident, 1.76 MB).
// One thread per (face, vertex) for full latency hiding (330K threads).
__global__ void gather_face_attr_kernel(const float* __restrict__ vc,
                                        const int* __restrict__ faces,
                                        float* __restrict__ fa_f, int n3) {
    int t = blockIdx.x * blockDim.x + threadIdx.x;
    if (t >= n3) return;
    int f = t / 3;
    int j = t - 3 * f;
    int v = faces[t];
    fa_f[4 * f + j] = vc[(long long)v * VC_C];
}

// Kernel 2: 8 pixels per thread. Nontemporal streaming loads/stores keep L2
// reserved for the fa gather table; 8 independent gathers in flight.
__global__ void seg_shader_kernel(const vfloat4* __restrict__ fa,
                                  const vint4* __restrict__ p2f4,
                                  const vfloat4* __restrict__ bary4,
                                  vint4* __restrict__ out4, int n8) {
    int i = blockIdx.x * blockDim.x + threadIdx.x;
    if (i >= n8) return;

    // 8 pixels: 2 int4 pf loads, 6 float4 bary loads (24 floats), 2 int4 stores
    const vint4 pfa = __builtin_nontemporal_load(p2f4 + 2 * (long long)i);
    const vint4 pfb = __builtin_nontemporal_load(p2f4 + 2 * (long long)i + 1);

    vfloat4 bb[6];
#pragma unroll
    for (int j = 0; j < 6; ++j)
        bb[j] = __builtin_nontemporal_load(bary4 + 6 * (long long)i + j);
    const float* w = reinterpret_cast<const float*>(bb);

    int pfv[8] = {pfa.x, pfa.y, pfa.z, pfa.w, pfb.x, pfb.y, pfb.z, pfb.w};

    // Issue all gathers first (independent), then consume.
    vfloat4 a[8];
#pragma unroll
    for (int j = 0; j < 8; ++j) {
        int f = pfv[j] >= 0 ? pfv[j] : 0;
        a[j] = fa[f];
    }

    int res[8];
#pragma unroll
    for (int j = 0; j < 8; ++j) {
        float s = w[3 * j + 0] * a[j].x + w[3 * j + 1] * a[j].y +
                  w[3 * j + 2] * a[j].z;
        res[j] = pfv[j] >= 0 ? (int)s : 0;  // trunc toward zero == astype(int32)
    }

    vint4 o0 = {res[0], res[1], res[2], res[3]};
    vint4 o1 = {res[4], res[5], res[6], res[7]};
    __builtin_nontemporal_store(o0, out4 + 2 * (long long)i);
    __builtin_nontemporal_store(o1, out4 + 2 * (long long)i + 1);
}

// Fallback (no workspace): direct gathers, 1 pixel per thread.
__global__ void seg_shader_direct_kernel(const float* __restrict__ vc,
                                         const int* __restrict__ faces,
                                         const int* __restrict__ p2f,
                                         const float* __restrict__ bary,
                                         int* __restrict__ out, int npix) {
    int i = blockIdx.x * blockDim.x + threadIdx.x;
    if (i >= npix) return;
    int f = p2f[i];
    int r = 0;
    if (f >= 0) {
        int v0 = faces[3 * f + 0];
        int v1 = faces[3 * f + 1];
        int v2 = faces[3 * f + 2];
        float w0 = bary[3 * (long long)i + 0];
        float w1 = bary[3 * (long long)i + 1];
        float w2 = bary[3 * (long long)i + 2];
        float s = w0 * vc[(long long)v0 * VC_C] +
                  w1 * vc[(long long)v1 * VC_C] +
                  w2 * vc[(long long)v2 * VC_C];
        r = (int)s;
    }
    out[i] = r;
}

extern "C" void kernel_launch(void* const* d_in, const int* in_sizes, int n_in,
                              void* d_out, int out_size, void* d_ws, size_t ws_size,
                              hipStream_t stream) {
    const float* verts_class = (const float*)d_in[0];   // [B*V*C] f32
    const int*   faces       = (const int*)d_in[1];     // [FTOT*3] i32
    const int*   pix_to_face = (const int*)d_in[2];     // [npix] i32
    const float* bary        = (const float*)d_in[3];   // [npix*3] f32
    int*         out         = (int*)d_out;             // [npix] i32

    const int ftot = in_sizes[1] / 3;
    const int npix = out_size;
    const size_t fa_bytes = (size_t)ftot * 4 * sizeof(float);

    if (d_ws != nullptr && ws_size >= fa_bytes && (npix % 8) == 0) {
        float* fa_f = (float*)d_ws;
        {
            int n3 = ftot * 3;
            int threads = 256;
            int blocks = (n3 + threads - 1) / threads;
            gather_face_attr_kernel<<<blocks, threads, 0, stream>>>(
                verts_class, faces, fa_f, n3);
        }
        {
            int n8 = npix / 8;
            int threads = 256;
            int blocks = (n8 + threads - 1) / threads;
            seg_shader_kernel<<<blocks, threads, 0, stream>>>(
                (const vfloat4*)d_ws, (const vint4*)pix_to_face,
                (const vfloat4*)bary, (vint4*)out, n8);
        }
    } else {
        int threads = 256;
        int blocks = (npix + threads - 1) / threads;
        seg_shader_direct_kernel<<<blocks, threads, 0, stream>>>(
            verts_class, faces, pix_to_face, bary, out, npix);
    }
}

// Round 4
// 30.463 us; speedup vs baseline: 1.1251x; 1.1251x over previous
//
#include <hip/hip_runtime.h>

// Problem constants (from reference):
//   B=8, V=6890, C=16, F=13776, FTOT=B*F=110208, H=W=512, K=1
//   npix = B*H*W*K = 2,097,152
// Output: int32 [B,H,W,K] = channel 0 of barycentric-interpolated
// per-vertex class features, truncated toward zero; 0 for background.
//
// Structure: prologue gathers per-face ch0 attrs into a 1.76 MB float4 table
// (L2-resident); main kernel = 4 px/thread (round-1 structure, 8 waves/SIMD)
// with NONTEMPORAL streaming loads/stores so the L2 keeps the table hot.

#define VC_C 16

// Native clang vector types — required for __builtin_nontemporal_*.
typedef int   vint4   __attribute__((ext_vector_type(4)));
typedef float vfloat4 __attribute__((ext_vector_type(4)));

// Kernel 1: one thread per (face, vertex); 330K threads for latency hiding.
__global__ void gather_face_attr_kernel(const float* __restrict__ vc,
                                        const int* __restrict__ faces,
                                        float* __restrict__ fa_f, int n3) {
    int t = blockIdx.x * blockDim.x + threadIdx.x;
    if (t >= n3) return;
    int f = t / 3;
    int j = t - 3 * f;
    int v = faces[t];
    fa_f[4 * f + j] = vc[(long long)v * VC_C];
}

// Kernel 2: 4 pixels per thread (round-1 structure). Streaming traffic is
// nontemporal; fa gathers use normal (cached) loads.
__global__ void seg_shader_kernel(const vfloat4* __restrict__ fa,
                                  const vint4* __restrict__ p2f4,
                                  const vfloat4* __restrict__ bary4,
                                  vint4* __restrict__ out4, int n4) {
    int i = blockIdx.x * blockDim.x + threadIdx.x;
    if (i >= n4) return;

    const vint4 pf = __builtin_nontemporal_load(p2f4 + (long long)i);

    vfloat4 b0 = __builtin_nontemporal_load(bary4 + 3 * (long long)i + 0);
    vfloat4 b1 = __builtin_nontemporal_load(bary4 + 3 * (long long)i + 1);
    vfloat4 b2 = __builtin_nontemporal_load(bary4 + 3 * (long long)i + 2);

    float w[12] = {b0.x, b0.y, b0.z, b0.w,
                   b1.x, b1.y, b1.z, b1.w,
                   b2.x, b2.y, b2.z, b2.w};
    int pfv[4] = {pf.x, pf.y, pf.z, pf.w};

    // Issue all gathers first (independent), then consume.
    vfloat4 a[4];
#pragma unroll
    for (int j = 0; j < 4; ++j) {
        int f = pfv[j] >= 0 ? pfv[j] : 0;
        a[j] = fa[f];
    }

    int res[4];
#pragma unroll
    for (int j = 0; j < 4; ++j) {
        float s = w[3 * j + 0] * a[j].x + w[3 * j + 1] * a[j].y +
                  w[3 * j + 2] * a[j].z;
        res[j] = pfv[j] >= 0 ? (int)s : 0;  // trunc toward zero == astype(int32)
    }

    vint4 o = {res[0], res[1], res[2], res[3]};
    __builtin_nontemporal_store(o, out4 + (long long)i);
}

// Fallback (no workspace): direct gathers, 1 pixel per thread.
__global__ void seg_shader_direct_kernel(const float* __restrict__ vc,
                                         const int* __restrict__ faces,
                                         const int* __restrict__ p2f,
                                         const float* __restrict__ bary,
                                         int* __restrict__ out, int npix) {
    int i = blockIdx.x * blockDim.x + threadIdx.x;
    if (i >= npix) return;
    int f = p2f[i];
    int r = 0;
    if (f >= 0) {
        int v0 = faces[3 * f + 0];
        int v1 = faces[3 * f + 1];
        int v2 = faces[3 * f + 2];
        float w0 = bary[3 * (long long)i + 0];
        float w1 = bary[3 * (long long)i + 1];
        float w2 = bary[3 * (long long)i + 2];
        float s = w0 * vc[(long long)v0 * VC_C] +
                  w1 * vc[(long long)v1 * VC_C] +
                  w2 * vc[(long long)v2 * VC_C];
        r = (int)s;
    }
    out[i] = r;
}

extern "C" void kernel_launch(void* const* d_in, const int* in_sizes, int n_in,
                              void* d_out, int out_size, void* d_ws, size_t ws_size,
                              hipStream_t stream) {
    const float* verts_class = (const float*)d_in[0];   // [B*V*C] f32
    const int*   faces       = (const int*)d_in[1];     // [FTOT*3] i32
    const int*   pix_to_face = (const int*)d_in[2];     // [npix] i32
    const float* bary        = (const float*)d_in[3];   // [npix*3] f32
    int*         out         = (int*)d_out;             // [npix] i32

    const int ftot = in_sizes[1] / 3;
    const int npix = out_size;
    const size_t fa_bytes = (size_t)ftot * 4 * sizeof(float);

    if (d_ws != nullptr && ws_size >= fa_bytes && (npix % 4) == 0) {
        float* fa_f = (float*)d_ws;
        {
            int n3 = ftot * 3;
            int threads = 256;
            int blocks = (n3 + threads - 1) / threads;
            gather_face_attr_kernel<<<blocks, threads, 0, stream>>>(
                verts_class, faces, fa_f, n3);
        }
        {
            int n4 = npix / 4;
            int threads = 256;
            int blocks = (n4 + threads - 1) / threads;
            seg_shader_kernel<<<blocks, threads, 0, stream>>>(
                (const vfloat4*)d_ws, (const vint4*)pix_to_face,
                (const vfloat4*)bary, (vint4*)out, n4);
        }
    } else {
        int threads = 256;
        int blocks = (npix + threads - 1) / threads;
        seg_shader_direct_kernel<<<blocks, threads, 0, stream>>>(
            verts_class, faces, pix_to_face, bary, out, npix);
    }
}

// Round 5
// 25.287 us; speedup vs baseline: 1.3554x; 1.2047x over previous
//
#include <hip/hip_runtime.h>

// Problem constants (from reference):
//   B=8, V=6890, C=16, F=13776, FTOT=B*F=110208, H=W=512, K=1
//   npix = B*H*W*K = 2,097,152
// Output: int32 [B,H,W,K] = channel 0 of barycentric-interpolated
// per-vertex class features, truncated toward zero; 0 for background.
//
// Structure (round 5): prologue gathers per-face ch0 attrs into a 1.76 MB
// float4 table (L2-resident); main kernel = 1 px/thread for MAX occupancy
// (32768 waves, 128 waves/CU) — round 3 showed the kernel is latency-bound
// (halving waves cost +7 µs), so go the other direction. No nontemporal
// hints (round 4 showed nt costs ~3 µs).

#define VC_C 16

typedef float vfloat4 __attribute__((ext_vector_type(4)));

// Kernel 1: one thread per (face, vertex); 330K threads for latency hiding.
__global__ void gather_face_attr_kernel(const float* __restrict__ vc,
                                        const int* __restrict__ faces,
                                        float* __restrict__ fa_f, int n3) {
    int t = blockIdx.x * blockDim.x + threadIdx.x;
    if (t >= n3) return;
    int f = t / 3;
    int j = t - 3 * f;
    int v = faces[t];
    fa_f[4 * f + j] = vc[(long long)v * VC_C];
}

// Kernel 2: 1 pixel per thread. Coalesced streaming loads; one float4 gather
// per valid pixel from the L2-resident table.
__global__ void seg_shader_kernel(const vfloat4* __restrict__ fa,
                                  const int* __restrict__ p2f,
                                  const float* __restrict__ bary,
                                  int* __restrict__ out, int npix) {
    int i = blockIdx.x * blockDim.x + threadIdx.x;
    if (i >= npix) return;

    int f = p2f[i];
    float w0 = bary[3 * (long long)i + 0];
    float w1 = bary[3 * (long long)i + 1];
    float w2 = bary[3 * (long long)i + 2];

    vfloat4 a = fa[f >= 0 ? f : 0];
    float s = w0 * a.x + w1 * a.y + w2 * a.z;
    out[i] = f >= 0 ? (int)s : 0;  // trunc toward zero == astype(int32)
}

// Fallback (no workspace): direct gathers, 1 pixel per thread.
__global__ void seg_shader_direct_kernel(const float* __restrict__ vc,
                                         const int* __restrict__ faces,
                                         const int* __restrict__ p2f,
                                         const float* __restrict__ bary,
                                         int* __restrict__ out, int npix) {
    int i = blockIdx.x * blockDim.x + threadIdx.x;
    if (i >= npix) return;
    int f = p2f[i];
    int r = 0;
    if (f >= 0) {
        int v0 = faces[3 * f + 0];
        int v1 = faces[3 * f + 1];
        int v2 = faces[3 * f + 2];
        float w0 = bary[3 * (long long)i + 0];
        float w1 = bary[3 * (long long)i + 1];
        float w2 = bary[3 * (long long)i + 2];
        float s = w0 * vc[(long long)v0 * VC_C] +
                  w1 * vc[(long long)v1 * VC_C] +
                  w2 * vc[(long long)v2 * VC_C];
        r = (int)s;
    }
    out[i] = r;
}

extern "C" void kernel_launch(void* const* d_in, const int* in_sizes, int n_in,
                              void* d_out, int out_size, void* d_ws, size_t ws_size,
                              hipStream_t stream) {
    const float* verts_class = (const float*)d_in[0];   // [B*V*C] f32
    const int*   faces       = (const int*)d_in[1];     // [FTOT*3] i32
    const int*   pix_to_face = (const int*)d_in[2];     // [npix] i32
    const float* bary        = (const float*)d_in[3];   // [npix*3] f32
    int*         out         = (int*)d_out;             // [npix] i32

    const int ftot = in_sizes[1] / 3;
    const int npix = out_size;
    const size_t fa_bytes = (size_t)ftot * 4 * sizeof(float);

    if (d_ws != nullptr && ws_size >= fa_bytes) {
        float* fa_f = (float*)d_ws;
        {
            int n3 = ftot * 3;
            int threads = 256;
            int blocks = (n3 + threads - 1) / threads;
            gather_face_attr_kernel<<<blocks, threads, 0, stream>>>(
                verts_class, faces, fa_f, n3);
        }
        {
            int threads = 256;
            int blocks = (npix + threads - 1) / threads;
            seg_shader_kernel<<<blocks, threads, 0, stream>>>(
                (const vfloat4*)d_ws, pix_to_face, bary, out, npix);
        }
    } else {
        int threads = 256;
        int blocks = (npix + threads - 1) / threads;
        seg_shader_direct_kernel<<<blocks, threads, 0, stream>>>(
            verts_class, faces, pix_to_face, bary, out, npix);
    }
}